// Round 4
// baseline (6308.028 us; speedup 1.0000x reference)
//
#include <hip/hip_runtime.h>
#include <stdint.h>

// ---------------------------------------------------------------------------
// Fused spiking-MLP forward: 20 timesteps, B=16384, 784 -> 400 -> 10.
//
// RNG: jax threefry, PARTITIONABLE semantics (verified absmax 0.0):
//   key_t = TF((0,42),(0,t)); per element e: bits = x0^x1 of TF(key_t,(0,e));
//   u = bitcast((bits>>9)|0x3f800000)-1.0f; xi = (x > u).
//
// V5 (vs V4 @5076us). Counter evidence: WRITE_SIZE 0.64->73MB in V4 =
// scratch spill (live state pushed past the 128-VGPR cap of
// launch_bounds(512,4)); per-SIMD VALU issue utilization only ~20-30%
// (VALUBusy is CU-any) -> the kernel is in-order ISSUE-STALL bound: 8
// SCC-dependent scalar branches per dt serialize the stream and ~3.4
// waves/SIMD (capped by 64 VGPRs of f64 accumulator state) can't cover
// the bubbles. Fix: BRANCHLESS hot loop. Gate bits are wave-uniform ->
// uniform double g = bit ? 1.0 : 0.0 (s_cselect, dual-issued SALU) and
// mem = fma(wd, g, mem), exact for g in {0,1}, same add order ->
// bit-identical. 32 independent v_fma_f64 per dt, zero branches, fully
// pipelineable. Dropped the manual wd pipeline + early-mask precompute
// (not needed without branches) -> live state back under 128 VGPR, no
// spill. Core structure as V3/V4: TD=8 f64 double-buffered W1 tile, one
// barrier per tile, two timesteps per sweep, dense branchless layer 2.
// ---------------------------------------------------------------------------

#define BSZ    16384
#define INDIM  784
#define HID    400
#define ODIM   10
#define TSTEPS 20

#define TD   8            // d-tile size
#define NT   98           // 784/8 tiles per sweep
#define WTJ  512          // padded neuron rows in LDS tile (400 real)
#define XIW  26           // xi words per sample
#define SPW  14           // spike words per sample

__device__ __forceinline__ void tfr(uint32_t& x0, uint32_t& x1, int r) {
  x0 += x1;
  x1 = (x1 << r) | (x1 >> (32 - r));
  x1 ^= x0;
}

__device__ __forceinline__ uint2 tf2x32(uint32_t k0, uint32_t k1,
                                        uint32_t c0, uint32_t c1) {
  uint32_t k2 = k0 ^ k1 ^ 0x1BD11BDAu;
  uint32_t x0 = c0 + k0, x1 = c1 + k1;
  tfr(x0,x1,13); tfr(x0,x1,15); tfr(x0,x1,26); tfr(x0,x1,6);
  x0 += k1; x1 += k2 + 1u;
  tfr(x0,x1,17); tfr(x0,x1,29); tfr(x0,x1,16); tfr(x0,x1,24);
  x0 += k2; x1 += k0 + 2u;
  tfr(x0,x1,13); tfr(x0,x1,15); tfr(x0,x1,26); tfr(x0,x1,6);
  x0 += k0; x1 += k1 + 3u;
  tfr(x0,x1,17); tfr(x0,x1,29); tfr(x0,x1,16); tfr(x0,x1,24);
  x0 += k1; x1 += k2 + 4u;
  tfr(x0,x1,13); tfr(x0,x1,15); tfr(x0,x1,26); tfr(x0,x1,6);
  x0 += k2; x1 += k0 + 5u;
  return make_uint2(x0, x1);
}

__device__ __forceinline__ float bits_to_unif(uint32_t b) {
  return __uint_as_float((b >> 9) | 0x3f800000u) - 1.0f;
}

__global__ __launch_bounds__(512, 4)
void snn_fused(const float* __restrict__ x,  const float* __restrict__ W1,
               const float* __restrict__ b1, const float* __restrict__ W2,
               const float* __restrict__ b2, float* __restrict__ out) {
  __shared__ double   wt[2][TD * WTJ];     // 65536 B, double-buffered [dt][j]
  __shared__ uint32_t xib[2][16][XIW];     // 3328 B  (xi bits for t0,t1)
  __shared__ uint32_t spk[16][SPW];        // 896 B

  const int tid  = threadIdx.x;            // 0..511
  const int g    = blockIdx.x;             // 0..1023
  const int wv   = tid >> 6;               // wave 0..7
  const int sg   = wv >> 1;                // sample group 0..3 (4 samples)
  const int kh   = wv & 1;                 // neuron half: j base 0 / 256
  const int lane = tid & 63;
  const int jb   = 256 * kh + lane;        // neuron j for k=0

  // zero padded j rows (j in [400,512)) in BOTH buffers once
  for (int i = tid; i < 2 * TD * WTJ; i += 512)
    if ((i & (WTJ - 1)) >= HID) (&wt[0][0])[i] = 0.0;

  // biases of owned neurons (j >= 400 dummies stay 0 -> never fire)
  double bb[4];
#pragma unroll
  for (int k = 0; k < 4; ++k) {
    const int j = jb + 64 * k;
    bb[k] = (j < HID) ? (double)b1[j] : 0.0;
  }

  // persistent layer-1 state: samples 4sg+s, neurons j = jb + 64k
  double   mem1[4][4];
  double   acc1[4][4];
  uint32_t spv[4];
#pragma unroll
  for (int s = 0; s < 4; ++s) {
    spv[s] = 0u;
#pragma unroll
    for (int k = 0; k < 4; ++k) { mem1[s][k] = 0.0; acc1[s][k] = 0.0; }
  }

  // layer-2 ownership: tid<160 -> (sample ls, output lo)
  const int ls = tid / ODIM;
  const int lo = tid - ls * ODIM;
  double m2 = 0.0;
  int    s2 = 0, cnt2 = 0;
  const double b2r = (tid < 160) ? (double)b2[lo] : 0.0;

  // Dense branchless layer-2: ascending-j gated adds (same order the old
  // ffs scan produced -> bit-identical). fma(w, bit, dot) is exact for
  // bit in {0,1}. float4 loads pipeline freely (no dependent control).
  auto layer2_step = [&]() {
    if (tid < 160) {
      double a2  = s2 ? 0.0 : m2 * 0.2;
      double dot = 0.0;
      const float4* w2p = (const float4*)(W2 + lo * HID);
      for (int m = 0; m < 12; ++m) {       // words 0..11 -> j 0..383
        const uint32_t word = spk[ls][m];
#pragma unroll
        for (int q = 0; q < 8; ++q) {
          const float4 v4 = w2p[8 * m + q];
          const float wf[4] = { v4.x, v4.y, v4.z, v4.w };
#pragma unroll
          for (int e = 0; e < 4; ++e) {
            const double bit = (double)((word >> (4 * q + e)) & 1u);
            dot = fma((double)wf[e], bit, dot);
          }
        }
      }
      {                                    // word 12, j 384..399 (16 bits)
        const uint32_t word = spk[ls][12];
#pragma unroll
        for (int q = 0; q < 4; ++q) {
          const float4 v4 = w2p[96 + q];
          const float wf[4] = { v4.x, v4.y, v4.z, v4.w };
#pragma unroll
          for (int e = 0; e < 4; ++e) {
            const double bit = (double)((word >> (4 * q + e)) & 1u);
            dot = fma((double)wf[e], bit, dot);
          }
        }
      }
      m2 = (a2 + dot) + b2r;
      s2 = (m2 > 0.5) ? 1 : 0;
      cnt2 += s2;
    }
  };

  // ---- prime the pipeline: buf0 <- tile 0, regs <- tile 1 ----
  const bool stager = (tid < HID);
  float4 va = make_float4(0,0,0,0), vb = va;
  if (stager) {
    const float4* s0 = (const float4*)(W1 + tid * INDIM);
    va = s0[0]; vb = s0[1];                // tile 0 (8 floats)
    double* dst = &wt[0][tid];
    dst[0*WTJ] = (double)va.x;  dst[1*WTJ] = (double)va.y;
    dst[2*WTJ] = (double)va.z;  dst[3*WTJ] = (double)va.w;
    dst[4*WTJ] = (double)vb.x;  dst[5*WTJ] = (double)vb.y;
    dst[6*WTJ] = (double)vb.z;  dst[7*WTJ] = (double)vb.w;
    const float4* s1 = (const float4*)(W1 + tid * INDIM + TD);
    va = s1[0]; vb = s1[1];                // tile 1
  }
  int cur = 0;
  int ld  = 2;                             // next tile index to load (mod NT)
  __syncthreads();                         // buf0 + pad zeros visible

  for (int tp = 0; tp < TSTEPS / 2; ++tp) {
    // ---- step keys for the pair ----
    const uint2 ka = tf2x32(0u, 42u, 0u, (uint32_t)(2 * tp));
    const uint2 kb = tf2x32(0u, 42u, 0u, (uint32_t)(2 * tp + 1));
    const uint32_t kx[2] = { ka.x, kb.x };
    const uint32_t ky[2] = { ka.y, kb.y };

    // ---- xi generation for BOTH steps; c-range split across kh pair ----
    const int cA = kh ? 7 : 0;
    const int cB = kh ? 13 : 7;
    for (int s = 0; s < 4; ++s) {
      const int q   = 4 * sg + s;
      const int row = g * 8 + (q & 7) + ((q >= 8) ? 8192 : 0);
      for (int c = cA; c < cB; ++c) {
        const int d = c * 64 + lane;
        const bool valid = (d < INDIM);
        float xv = 0.0f;
        if (valid) xv = x[row * INDIM + d];
        const uint32_t e = (uint32_t)row * (uint32_t)INDIM + (uint32_t)d;
#pragma unroll
        for (int tt = 0; tt < 2; ++tt) {
          int xb = 0;
          if (valid) {
            uint2 r = tf2x32(kx[tt], ky[tt], 0u, e);
            xb = xv > bits_to_unif(r.x ^ r.y);
          }
          unsigned long long m = __ballot(xb);
          if (lane == 0) {
            xib[tt][q][2*c]     = (uint32_t)m;
            xib[tt][q][2*c + 1] = (uint32_t)(m >> 32);
          }
        }
      }
    }
    __syncthreads();                       // xib visible to both kh waves

    // ---- decay + reset into t0 accumulator; zero t1 accumulator ----
#pragma unroll
    for (int s = 0; s < 4; ++s)
#pragma unroll
      for (int k = 0; k < 4; ++k) {
        mem1[s][k] = ((spv[s] >> k) & 1u) ? 0.0 : mem1[s][k] * 0.2;
        acc1[s][k] = 0.0;
      }

    // ---- ONE sweep over 98 tiles feeds BOTH timesteps (double-buffered) --
    for (int td = 0; td < NT; ++td) {
      // stage tile td+1 into buf^1 (overlaps consume of buf), then
      // prefetch tile 'ld' from global (lands during next consume phase)
      if (stager) {
        double* dst = &wt[cur ^ 1][tid];
        dst[0*WTJ] = (double)va.x;  dst[1*WTJ] = (double)va.y;
        dst[2*WTJ] = (double)va.z;  dst[3*WTJ] = (double)va.w;
        dst[4*WTJ] = (double)vb.x;  dst[5*WTJ] = (double)vb.y;
        dst[6*WTJ] = (double)vb.z;  dst[7*WTJ] = (double)vb.w;
        const float4* src = (const float4*)(W1 + tid * INDIM + ld * TD);
        va = src[0]; vb = src[1];
      }
      ld = (ld + 1 == NT) ? 0 : ld + 1;

      // xi bit-words for this tile, hoisted to SGPR (wave-uniform)
      const int wi = td >> 2, sh = (td & 3) * 8;
      uint32_t bA[4], bB[4];
#pragma unroll
      for (int s = 0; s < 4; ++s) {
        bA[s] = (uint32_t)__builtin_amdgcn_readfirstlane(
                  (int)((xib[0][4*sg + s][wi] >> sh) & 0xFFu));
        bB[s] = (uint32_t)__builtin_amdgcn_readfirstlane(
                  (int)((xib[1][4*sg + s][wi] >> sh) & 0xFFu));
      }

      const double* wp = &wt[cur][jb];

      // branchless: uniform f64 gates (s_cselect) feed v_fma_f64 streams.
      // 32 independent FMAs per dt, zero control flow.
#pragma unroll
      for (int dt = 0; dt < TD; ++dt) {
        double wd[4];
#pragma unroll
        for (int k = 0; k < 4; ++k)
          wd[k] = wp[dt * WTJ + 64 * k];   // ds_read_b64, 2-way (free)
#pragma unroll
        for (int s = 0; s < 4; ++s) {
          const double gA = (bA[s] & (1u << dt)) ? 1.0 : 0.0;
          const double gB = (bB[s] & (1u << dt)) ? 1.0 : 0.0;
#pragma unroll
          for (int k = 0; k < 4; ++k)
            mem1[s][k] = fma(wd[k], gA, mem1[s][k]);
#pragma unroll
          for (int k = 0; k < 4; ++k)
            acc1[s][k] = fma(wd[k], gB, acc1[s][k]);
        }
      }

      __syncthreads();                     // buf consumed; buf^1 ready
      cur ^= 1;
    }

    // ---- finalize t0: + b1, threshold, pack spikes ----
#pragma unroll
    for (int s = 0; s < 4; ++s) {
      uint32_t m = 0u;
#pragma unroll
      for (int k = 0; k < 4; ++k) {
        mem1[s][k] += bb[k];
        if (mem1[s][k] > 0.5) m |= (1u << k);
      }
      spv[s] = m;
#pragma unroll
      for (int k = 0; k < 4; ++k) {
        unsigned long long bm = __ballot((m >> k) & 1u);
        const int w0 = 8 * kh + 2 * k;
        if (lane == 0 && w0 < SPW) {
          spk[4*sg + s][w0]     = (uint32_t)bm;
          spk[4*sg + s][w0 + 1] = (uint32_t)(bm >> 32);
        }
      }
    }
    __syncthreads();                       // spikes(t0) visible
    layer2_step();                         // t0
    __syncthreads();                       // spk consumed

    // ---- finalize t1: decay(t0) + acc1 + b1, threshold, pack ----
#pragma unroll
    for (int s = 0; s < 4; ++s) {
      uint32_t m = 0u;
#pragma unroll
      for (int k = 0; k < 4; ++k) {
        double v = ((spv[s] >> k) & 1u) ? 0.0 : mem1[s][k] * 0.2;
        v += acc1[s][k];
        v += bb[k];
        mem1[s][k] = v;
        if (v > 0.5) m |= (1u << k);
      }
      spv[s] = m;
#pragma unroll
      for (int k = 0; k < 4; ++k) {
        unsigned long long bm = __ballot((m >> k) & 1u);
        const int w0 = 8 * kh + 2 * k;
        if (lane == 0 && w0 < SPW) {
          spk[4*sg + s][w0]     = (uint32_t)bm;
          spk[4*sg + s][w0 + 1] = (uint32_t)(bm >> 32);
        }
      }
    }
    __syncthreads();                       // spikes(t1) visible
    layer2_step();                         // t1
    // next pair: xi-gen then its barrier protect xib/spk before reuse
  }

  // ---- output: h2_sum / 20 ----
  if (tid < 160) {
    const int row = g * 8 + (ls & 7) + ((ls >= 8) ? 8192 : 0);
    out[row * ODIM + lo] = (float)((double)cnt2 / 20.0);
  }
}

extern "C" void kernel_launch(void* const* d_in, const int* in_sizes, int n_in,
                              void* d_out, int out_size, void* d_ws, size_t ws_size,
                              hipStream_t stream) {
  const float* x  = (const float*)d_in[0];
  const float* W1 = (const float*)d_in[1];
  const float* b1 = (const float*)d_in[2];
  const float* W2 = (const float*)d_in[3];
  const float* b2 = (const float*)d_in[4];
  // d_in[5] = time_window (int, ==20) — compile-time constant here.
  float* out = (float*)d_out;
  hipLaunchKernelGGL(snn_fused, dim3(1024), dim3(512), 0, stream,
                     x, W1, b1, W2, b2, out);
}

// Round 5
// 5078.881 us; speedup vs baseline: 1.2420x; 1.2420x over previous
//
#include <hip/hip_runtime.h>
#include <stdint.h>

// ---------------------------------------------------------------------------
// Fused spiking-MLP forward: 20 timesteps, B=16384, 784 -> 400 -> 10.
//
// RNG: jax threefry, PARTITIONABLE semantics (verified absmax 0.0):
//   key_t = TF((0,42),(0,t)); per element e: bits = x0^x1 of TF(key_t,(0,e));
//   u = bitcast((bits>>9)|0x3f800000)-1.0f; xi = (x > u).
//
// V6 (vs V4 @5076 / V5 @6308). Model recalibration: VALUBusy is a CU-level
// "any SIMD issuing" metric; per-SIMD issue is only ~20-30% -> stall-bound.
// Branchy gating (half the f64 issue of branchless) is the right hot loop
// (V5's branchless 2x-issue + persistent spill regressed). The confirmed
// fixable loss is the SPILL (WRITE_SIZE 0.64->61-73MB in V4/V5): during
// layer2(t0) both mem1 (32 VGPR) and acc1 (32 VGPR) plus ~40 L2 temps were
// live -> >128 VGPR. Fixes:
//  * Epilogue reorder: finalize t0 AND t1 first (acc1 dies), then one
//    barrier, then layer2(t0); layer2(t1). spk double-set [2][16][SPW].
//  * Lean dense layer-2: one float4 + nibble per iter, 4 partial f64 dots
//    (f64 reorder safe: ~1e-15 perturbation vs ~1e-6-density spike margin).
//    No barrier after -> its serial fma chain overlaps next pair's xi-gen.
//  * Hot loop = exact V3 form (no wd pipeline / early masks: reg cost,
//    unproven gain).
// Core: TD=8 f64 double-buffered W1 tile, 1 barrier/tile, 2 timesteps per
// sweep, 8 waves = 4 sample-groups x 2 neuron-halves, SGPR-hoisted xi bits
// -> scalar-branch-gated f64 adds.
// ---------------------------------------------------------------------------

#define BSZ    16384
#define INDIM  784
#define HID    400
#define ODIM   10
#define TSTEPS 20

#define TD   8            // d-tile size
#define NT   98           // 784/8 tiles per sweep
#define WTJ  512          // padded neuron rows in LDS tile (400 real)
#define XIW  26           // xi words per sample
#define SPW  14           // spike words per sample

__device__ __forceinline__ void tfr(uint32_t& x0, uint32_t& x1, int r) {
  x0 += x1;
  x1 = (x1 << r) | (x1 >> (32 - r));
  x1 ^= x0;
}

__device__ __forceinline__ uint2 tf2x32(uint32_t k0, uint32_t k1,
                                        uint32_t c0, uint32_t c1) {
  uint32_t k2 = k0 ^ k1 ^ 0x1BD11BDAu;
  uint32_t x0 = c0 + k0, x1 = c1 + k1;
  tfr(x0,x1,13); tfr(x0,x1,15); tfr(x0,x1,26); tfr(x0,x1,6);
  x0 += k1; x1 += k2 + 1u;
  tfr(x0,x1,17); tfr(x0,x1,29); tfr(x0,x1,16); tfr(x0,x1,24);
  x0 += k2; x1 += k0 + 2u;
  tfr(x0,x1,13); tfr(x0,x1,15); tfr(x0,x1,26); tfr(x0,x1,6);
  x0 += k0; x1 += k1 + 3u;
  tfr(x0,x1,17); tfr(x0,x1,29); tfr(x0,x1,16); tfr(x0,x1,24);
  x0 += k1; x1 += k2 + 4u;
  tfr(x0,x1,13); tfr(x0,x1,15); tfr(x0,x1,26); tfr(x0,x1,6);
  x0 += k2; x1 += k0 + 5u;
  return make_uint2(x0, x1);
}

__device__ __forceinline__ float bits_to_unif(uint32_t b) {
  return __uint_as_float((b >> 9) | 0x3f800000u) - 1.0f;
}

__global__ __launch_bounds__(512, 4)
void snn_fused(const float* __restrict__ x,  const float* __restrict__ W1,
               const float* __restrict__ b1, const float* __restrict__ W2,
               const float* __restrict__ b2, float* __restrict__ out) {
  __shared__ double   wt[2][TD * WTJ];     // 65536 B, double-buffered [dt][j]
  __shared__ uint32_t xib[2][16][XIW];     // 3328 B  (xi bits for t0,t1)
  __shared__ uint32_t spk[2][16][SPW];     // 1792 B  (spikes for t0,t1)

  const int tid  = threadIdx.x;            // 0..511
  const int g    = blockIdx.x;             // 0..1023
  const int wv   = tid >> 6;               // wave 0..7
  const int sg   = wv >> 1;                // sample group 0..3 (4 samples)
  const int kh   = wv & 1;                 // neuron half: j base 0 / 256
  const int lane = tid & 63;
  const int jb   = 256 * kh + lane;        // neuron j for k=0

  // zero padded j rows (j in [400,512)) in BOTH buffers once
  for (int i = tid; i < 2 * TD * WTJ; i += 512)
    if ((i & (WTJ - 1)) >= HID) (&wt[0][0])[i] = 0.0;

  // biases of owned neurons (j >= 400 dummies stay 0 -> never fire)
  double bb[4];
#pragma unroll
  for (int k = 0; k < 4; ++k) {
    const int j = jb + 64 * k;
    bb[k] = (j < HID) ? (double)b1[j] : 0.0;
  }

  // persistent layer-1 state: samples 4sg+s, neurons j = jb + 64k
  double   mem1[4][4];
  double   acc1[4][4];
  uint32_t spv[4];
#pragma unroll
  for (int s = 0; s < 4; ++s) {
    spv[s] = 0u;
#pragma unroll
    for (int k = 0; k < 4; ++k) { mem1[s][k] = 0.0; acc1[s][k] = 0.0; }
  }

  // layer-2 ownership: tid<160 -> (sample ls, output lo)
  const int ls = tid / ODIM;
  const int lo = tid - ls * ODIM;
  double m2 = 0.0;
  int    s2 = 0, cnt2 = 0;
  const double b2r = (tid < 160) ? (double)b2[lo] : 0.0;

  // Lean dense layer-2: one float4 + spike-nibble per iteration, 4 partial
  // dots (f64 reorder safe). fma(w, bit, dot) exact for bit in {0,1}.
  auto layer2_step = [&](int tt) {
    if (tid < 160) {
      double a2 = s2 ? 0.0 : m2 * 0.2;
      double d0 = 0.0, d1 = 0.0, d2 = 0.0, d3 = 0.0;
      const float4* w2p = (const float4*)(W2 + lo * HID);
#pragma unroll 4
      for (int qq = 0; qq < 100; ++qq) {   // j = 4*qq .. 4*qq+3
        const uint32_t nib = (spk[tt][ls][qq >> 3] >> ((qq & 7) * 4)) & 0xFu;
        const float4 v4 = w2p[qq];
        d0 = fma((double)v4.x, (double)(nib & 1u),        d0);
        d1 = fma((double)v4.y, (double)((nib >> 1) & 1u), d1);
        d2 = fma((double)v4.z, (double)((nib >> 2) & 1u), d2);
        d3 = fma((double)v4.w, (double)((nib >> 3) & 1u), d3);
      }
      m2 = (a2 + ((d0 + d1) + (d2 + d3))) + b2r;
      s2 = (m2 > 0.5) ? 1 : 0;
      cnt2 += s2;
    }
  };

  // ---- prime the pipeline: buf0 <- tile 0, regs <- tile 1 ----
  const bool stager = (tid < HID);
  float4 va = make_float4(0,0,0,0), vb = va;
  if (stager) {
    const float4* s0 = (const float4*)(W1 + tid * INDIM);
    va = s0[0]; vb = s0[1];                // tile 0 (8 floats)
    double* dst = &wt[0][tid];
    dst[0*WTJ] = (double)va.x;  dst[1*WTJ] = (double)va.y;
    dst[2*WTJ] = (double)va.z;  dst[3*WTJ] = (double)va.w;
    dst[4*WTJ] = (double)vb.x;  dst[5*WTJ] = (double)vb.y;
    dst[6*WTJ] = (double)vb.z;  dst[7*WTJ] = (double)vb.w;
    const float4* s1 = (const float4*)(W1 + tid * INDIM + TD);
    va = s1[0]; vb = s1[1];                // tile 1
  }
  int cur = 0;
  int ld  = 2;                             // next tile index to load (mod NT)
  __syncthreads();                         // buf0 + pad zeros visible

  for (int tp = 0; tp < TSTEPS / 2; ++tp) {
    // ---- step keys for the pair ----
    const uint2 ka = tf2x32(0u, 42u, 0u, (uint32_t)(2 * tp));
    const uint2 kb = tf2x32(0u, 42u, 0u, (uint32_t)(2 * tp + 1));
    const uint32_t kx[2] = { ka.x, kb.x };
    const uint32_t ky[2] = { ka.y, kb.y };

    // ---- xi generation for BOTH steps; c-range split across kh pair ----
    const int cA = kh ? 7 : 0;
    const int cB = kh ? 13 : 7;
    for (int s = 0; s < 4; ++s) {
      const int q   = 4 * sg + s;
      const int row = g * 8 + (q & 7) + ((q >= 8) ? 8192 : 0);
      for (int c = cA; c < cB; ++c) {
        const int d = c * 64 + lane;
        const bool valid = (d < INDIM);
        float xv = 0.0f;
        if (valid) xv = x[row * INDIM + d];
        const uint32_t e = (uint32_t)row * (uint32_t)INDIM + (uint32_t)d;
#pragma unroll
        for (int tt = 0; tt < 2; ++tt) {
          int xb = 0;
          if (valid) {
            uint2 r = tf2x32(kx[tt], ky[tt], 0u, e);
            xb = xv > bits_to_unif(r.x ^ r.y);
          }
          unsigned long long m = __ballot(xb);
          if (lane == 0) {
            xib[tt][q][2*c]     = (uint32_t)m;
            xib[tt][q][2*c + 1] = (uint32_t)(m >> 32);
          }
        }
      }
    }
    __syncthreads();                       // xib visible to both kh waves

    // ---- decay + reset into t0 accumulator; zero t1 accumulator ----
#pragma unroll
    for (int s = 0; s < 4; ++s)
#pragma unroll
      for (int k = 0; k < 4; ++k) {
        mem1[s][k] = ((spv[s] >> k) & 1u) ? 0.0 : mem1[s][k] * 0.2;
        acc1[s][k] = 0.0;
      }

    // ---- ONE sweep over 98 tiles feeds BOTH timesteps (double-buffered) --
    for (int td = 0; td < NT; ++td) {
      // stage tile td+1 into buf^1 (overlaps consume of buf), then
      // prefetch tile 'ld' from global (lands during next consume phase)
      if (stager) {
        double* dst = &wt[cur ^ 1][tid];
        dst[0*WTJ] = (double)va.x;  dst[1*WTJ] = (double)va.y;
        dst[2*WTJ] = (double)va.z;  dst[3*WTJ] = (double)va.w;
        dst[4*WTJ] = (double)vb.x;  dst[5*WTJ] = (double)vb.y;
        dst[6*WTJ] = (double)vb.z;  dst[7*WTJ] = (double)vb.w;
        const float4* src = (const float4*)(W1 + tid * INDIM + ld * TD);
        va = src[0]; vb = src[1];
      }
      ld = (ld + 1 == NT) ? 0 : ld + 1;

      // xi bit-words for this tile, hoisted to SGPR (wave-uniform)
      const int wi = td >> 2, sh = (td & 3) * 8;
      uint32_t bA[4], bB[4];
#pragma unroll
      for (int s = 0; s < 4; ++s) {
        bA[s] = (uint32_t)__builtin_amdgcn_readfirstlane(
                  (int)((xib[0][4*sg + s][wi] >> sh) & 0xFFu));
        bB[s] = (uint32_t)__builtin_amdgcn_readfirstlane(
                  (int)((xib[1][4*sg + s][wi] >> sh) & 0xFFu));
      }

      const double* wp = &wt[cur][jb];
#pragma unroll
      for (int dt = 0; dt < TD; ++dt) {
        double wd[4];
#pragma unroll
        for (int k = 0; k < 4; ++k)
          wd[k] = wp[dt * WTJ + 64 * k];   // ds_read_b64, 2-way (free)
#pragma unroll
        for (int s = 0; s < 4; ++s) {
          if (bA[s] & (1u << dt)) {        // scalar test: s_and + s_cbranch
#pragma unroll
            for (int k = 0; k < 4; ++k) mem1[s][k] += wd[k];
          }
          if (bB[s] & (1u << dt)) {
#pragma unroll
            for (int k = 0; k < 4; ++k) acc1[s][k] += wd[k];
          }
        }
      }

      __syncthreads();                     // buf consumed; buf^1 ready
      cur ^= 1;
    }

    // ---- finalize t0: + b1, threshold, pack spikes -> spk[0] ----
#pragma unroll
    for (int s = 0; s < 4; ++s) {
      uint32_t m = 0u;
#pragma unroll
      for (int k = 0; k < 4; ++k) {
        mem1[s][k] += bb[k];
        if (mem1[s][k] > 0.5) m |= (1u << k);
      }
      spv[s] = m;
#pragma unroll
      for (int k = 0; k < 4; ++k) {
        unsigned long long bm = __ballot((m >> k) & 1u);
        const int w0 = 8 * kh + 2 * k;
        if (lane == 0 && w0 < SPW) {
          spk[0][4*sg + s][w0]     = (uint32_t)bm;
          spk[0][4*sg + s][w0 + 1] = (uint32_t)(bm >> 32);
        }
      }
    }

    // ---- finalize t1: decay(t0) + acc1 + b1, threshold -> spk[1] ----
    // (acc1 dies here, BEFORE layer2 runs -> no register overlap)
#pragma unroll
    for (int s = 0; s < 4; ++s) {
      uint32_t m = 0u;
#pragma unroll
      for (int k = 0; k < 4; ++k) {
        double v = ((spv[s] >> k) & 1u) ? 0.0 : mem1[s][k] * 0.2;
        v += acc1[s][k];
        v += bb[k];
        mem1[s][k] = v;
        if (v > 0.5) m |= (1u << k);
      }
      spv[s] = m;
#pragma unroll
      for (int k = 0; k < 4; ++k) {
        unsigned long long bm = __ballot((m >> k) & 1u);
        const int w0 = 8 * kh + 2 * k;
        if (lane == 0 && w0 < SPW) {
          spk[1][4*sg + s][w0]     = (uint32_t)bm;
          spk[1][4*sg + s][w0 + 1] = (uint32_t)(bm >> 32);
        }
      }
    }
    __syncthreads();                       // spikes(t0,t1) visible

    layer2_step(0);                        // t0
    layer2_step(1);                        // t1
    // no barrier: layer2's serial fma chain overlaps next pair's xi-gen;
    // next writes to spk are a full sweep (99 barriers) away.
  }

  // ---- output: h2_sum / 20 ----
  if (tid < 160) {
    const int row = g * 8 + (ls & 7) + ((ls >= 8) ? 8192 : 0);
    out[row * ODIM + lo] = (float)((double)cnt2 / 20.0);
  }
}

extern "C" void kernel_launch(void* const* d_in, const int* in_sizes, int n_in,
                              void* d_out, int out_size, void* d_ws, size_t ws_size,
                              hipStream_t stream) {
  const float* x  = (const float*)d_in[0];
  const float* W1 = (const float*)d_in[1];
  const float* b1 = (const float*)d_in[2];
  const float* W2 = (const float*)d_in[3];
  const float* b2 = (const float*)d_in[4];
  // d_in[5] = time_window (int, ==20) — compile-time constant here.
  float* out = (float*)d_out;
  hipLaunchKernelGGL(snn_fused, dim3(1024), dim3(512), 0, stream,
                     x, W1, b1, W2, b2, out);
}